// Round 1
// baseline (748.308 us; speedup 1.0000x reference)
//
#include <hip/hip_runtime.h>
#include <math.h>

typedef unsigned short u16;
typedef short short8 __attribute__((ext_vector_type(8)));
typedef float floatx4 __attribute__((ext_vector_type(4)));

#define SS 4
#define C_DIM 512
#define L_TOK 1024   // H*W

// ---------- helpers ----------
static __device__ __forceinline__ u16 f2bf(float f) {
  union { float f; unsigned u; } v; v.f = f;
  unsigned u = v.u;
  unsigned r = (u + 0x7fffu + ((u >> 16) & 1u)) >> 16;  // RNE
  return (u16)r;
}
static __device__ __forceinline__ void unpack8(uint4 u, float* dst, float scale) {
  dst[0] = __uint_as_float(u.x << 16) * scale;
  dst[1] = __uint_as_float(u.x & 0xffff0000u) * scale;
  dst[2] = __uint_as_float(u.y << 16) * scale;
  dst[3] = __uint_as_float(u.y & 0xffff0000u) * scale;
  dst[4] = __uint_as_float(u.z << 16) * scale;
  dst[5] = __uint_as_float(u.z & 0xffff0000u) * scale;
  dst[6] = __uint_as_float(u.w << 16) * scale;
  dst[7] = __uint_as_float(u.w & 0xffff0000u) * scale;
}

// ---------- fp32 -> bf16 weight conversion ----------
__global__ __launch_bounds__(256) void convert_bf16(const float* __restrict__ src,
                                                    u16* __restrict__ dst, int n4) {
  int i = blockIdx.x * 256 + threadIdx.x;
  if (i >= n4) return;
  float4 v = ((const float4*)src)[i];
  ushort4 o;
  o.x = f2bf(v.x); o.y = f2bf(v.y); o.z = f2bf(v.z); o.w = f2bf(v.w);
  ((ushort4*)dst)[i] = o;
}

// ---------- ada = silu(cond) @ ada_w.T + ada_b  [32, 3072] ----------
__global__ __launch_bounds__(256) void ada_kernel(const float* __restrict__ cond,
                                                  const float* __restrict__ w,
                                                  const float* __restrict__ bias,
                                                  float* __restrict__ ada) {
  int b = blockIdx.y;
  int j = blockIdx.x * 256 + threadIdx.x;   // < 3072
  __shared__ float sc[C_DIM];
  for (int c = threadIdx.x; c < C_DIM; c += 256) {
    float v = cond[b * C_DIM + c];
    sc[c] = v / (1.0f + expf(-v));
  }
  __syncthreads();
  const float* wr = w + (size_t)j * C_DIM;
  float acc = 0.f;
  for (int k = 0; k < C_DIM; k += 4) {
    float4 wv = *(const float4*)&wr[k];
    acc += sc[k] * wv.x + sc[k + 1] * wv.y + sc[k + 2] * wv.z + sc[k + 3] * wv.w;
  }
  ada[(size_t)b * 3072 + j] = acc + bias[j];
}

// ---------- LN + modulate (+ optional roll/window gather), output bf16 ----------
// MODE 0: LN1 path — gather from rolled+window-partitioned x, ada offsets 0/512
// MODE 1: LN2 path — direct rows of x_mid, ada offsets 1536/2048
template <int MODE>
__global__ __launch_bounds__(128) void ln_mod(const float* __restrict__ x,
                                              const float* __restrict__ ada,
                                              const float* __restrict__ nw,
                                              const float* __restrict__ nb,
                                              u16* __restrict__ out) {
  int m = blockIdx.x;           // output row (window layout for MODE 0)
  int b = m >> 10;
  size_t srow;
  if (MODE == 0) {
    int n = m & 63, widx = (m >> 6) & 15;
    int wh = widx >> 2, wwi = widx & 3;
    int i = n >> 3, j = n & 7;
    int hs = (wh * 8 + i + SS) & 31;
    int ws_ = (wwi * 8 + j + SS) & 31;
    srow = (size_t)b * L_TOK + hs * 32 + ws_;
  } else {
    srow = (size_t)m;
  }
  const float* src = x + srow * C_DIM;
  int t = threadIdx.x;
  float4 v = *(const float4*)&src[t * 4];
  float s = v.x + v.y + v.z + v.w;
  float ss = v.x * v.x + v.y * v.y + v.z * v.z + v.w * v.w;
#pragma unroll
  for (int off = 32; off > 0; off >>= 1) {
    s += __shfl_down(s, off);
    ss += __shfl_down(ss, off);
  }
  __shared__ float red[4];
  if ((t & 63) == 0) { red[(t >> 6) * 2] = s; red[(t >> 6) * 2 + 1] = ss; }
  __syncthreads();
  float mean = (red[0] + red[2]) * (1.f / C_DIM);
  float var = (red[1] + red[3]) * (1.f / C_DIM) - mean * mean;
  float rstd = rsqrtf(var + 1e-5f);
  const float* sh = ada + (size_t)b * 3072 + (MODE ? 1536 : 0);
  const float* scm = ada + (size_t)b * 3072 + (MODE ? 2048 : 512);
  int c = t * 4;
  ushort4 o;
  {
    float y;
    y = ((v.x - mean) * rstd * nw[c + 0] + nb[c + 0]) * (1.f + scm[c + 0]) + sh[c + 0]; o.x = f2bf(y);
    y = ((v.y - mean) * rstd * nw[c + 1] + nb[c + 1]) * (1.f + scm[c + 1]) + sh[c + 1]; o.y = f2bf(y);
    y = ((v.z - mean) * rstd * nw[c + 2] + nb[c + 2]) * (1.f + scm[c + 2]) + sh[c + 2]; o.z = f2bf(y);
    y = ((v.w - mean) * rstd * nw[c + 3] + nb[c + 3]) * (1.f + scm[c + 3]) + sh[c + 3]; o.w = f2bf(y);
  }
  *(ushort4*)&out[(size_t)m * C_DIM + c] = o;
}

// ---------- bf16 MFMA GEMM: out[M,N] = A[M,K] @ Bw[N,K]^T + bias ----------
// EPI 0: bias -> bf16            (qkv)
// EPI 1: bias, exact GELU -> bf16 (fc1)
// EPI 2: bias, window-reverse + roll scatter, x + g_msa*v -> fp32 d_out (proj)
// EPI 3: bias, d_out += g_mlp*v in place (fc2)
template <int EPI>
__global__ __launch_bounds__(256, 2) void gemm_bf16(
    const u16* __restrict__ A, const u16* __restrict__ Bw,
    const float* __restrict__ bias, int K, int N,
    u16* __restrict__ outBf, float* __restrict__ outF,
    const float* __restrict__ resid, const float* __restrict__ ada) {
  __shared__ __align__(16) u16 lA[128 * 32];
  __shared__ __align__(16) u16 lB[128 * 32];
  const int tid = threadIdx.x;
  const int lane = tid & 63, wave = tid >> 6;
  const int wr = wave >> 1, wc = wave & 1;
  const int rowA0 = blockIdx.y * 128;
  const int colB0 = blockIdx.x * 128;
  floatx4 acc[4][4];
#pragma unroll
  for (int a = 0; a < 4; a++)
#pragma unroll
    for (int b = 0; b < 4; b++) acc[a][b] = (floatx4){0.f, 0.f, 0.f, 0.f};

  const int r0 = tid >> 2, c0 = (tid & 3) * 8;  // staging chunk (16B = 8 bf16)
  const int r1 = r0 + 64;
  const int q = lane >> 4, fr = lane & 15;

  for (int k0 = 0; k0 < K; k0 += 32) {
    *(uint4*)&lA[r0 * 32 + c0] = *(const uint4*)&A[(size_t)(rowA0 + r0) * K + k0 + c0];
    *(uint4*)&lA[r1 * 32 + c0] = *(const uint4*)&A[(size_t)(rowA0 + r1) * K + k0 + c0];
    *(uint4*)&lB[r0 * 32 + c0] = *(const uint4*)&Bw[(size_t)(colB0 + r0) * K + k0 + c0];
    *(uint4*)&lB[r1 * 32 + c0] = *(const uint4*)&Bw[(size_t)(colB0 + r1) * K + k0 + c0];
    __syncthreads();
    short8 af[4], bfr[4];
#pragma unroll
    for (int mi = 0; mi < 4; mi++)
      af[mi] = *(const short8*)&lA[(wr * 64 + mi * 16 + fr) * 32 + q * 8];
#pragma unroll
    for (int ni = 0; ni < 4; ni++)
      bfr[ni] = *(const short8*)&lB[(wc * 64 + ni * 16 + fr) * 32 + q * 8];
#pragma unroll
    for (int mi = 0; mi < 4; mi++)
#pragma unroll
      for (int ni = 0; ni < 4; ni++)
        acc[mi][ni] = __builtin_amdgcn_mfma_f32_16x16x32_bf16(af[mi], bfr[ni], acc[mi][ni], 0, 0, 0);
    __syncthreads();
  }

#pragma unroll
  for (int mi = 0; mi < 4; mi++) {
#pragma unroll
    for (int ni = 0; ni < 4; ni++) {
      int col = colB0 + wc * 64 + ni * 16 + fr;
      float bv = bias[col];
#pragma unroll
      for (int r = 0; r < 4; r++) {
        int row = rowA0 + wr * 64 + mi * 16 + q * 4 + r;
        float v = acc[mi][ni][r] + bv;
        if (EPI == 0) {
          outBf[(size_t)row * N + col] = f2bf(v);
        } else if (EPI == 1) {
          v = 0.5f * v * (1.f + erff(v * 0.70710678118654752f));
          outBf[(size_t)row * N + col] = f2bf(v);
        } else if (EPI == 2) {
          int b = row >> 10;
          int n = row & 63, widx = (row >> 6) & 15;
          int wh = widx >> 2, wwi = widx & 3;
          int i = n >> 3, j = n & 7;
          int hd = (wh * 8 + i + SS) & 31;
          int wd = (wwi * 8 + j + SS) & 31;
          size_t dst = ((size_t)b * L_TOK + hd * 32 + wd) * C_DIM + col;
          outF[dst] = resid[dst] + ada[(size_t)b * 3072 + 1024 + col] * v;
        } else {
          int b = row >> 10;
          size_t dst = (size_t)row * C_DIM + col;
          outF[dst] = outF[dst] + ada[(size_t)b * 3072 + 2560 + col] * v;
        }
      }
    }
  }
}

// ---------- windowed attention: one block per (window, head) ----------
__global__ __launch_bounds__(256, 2) void attn_kernel(const u16* __restrict__ qkv,
                                                      const float* __restrict__ rpb,
                                                      u16* __restrict__ out) {
  const int blk = blockIdx.x;     // 8192 = 512 windows * 16 heads
  const int w_ = blk >> 4, head = blk & 15;
  const int widx = w_ & 15;
  const int wh = widx >> 2, wwi = widx & 3;
  __shared__ float qs[64][36];
  __shared__ float ks[64][36];
  __shared__ float vs[64][36];
  __shared__ float ps[64][66];
  const int t = threadIdx.x;
  const int n = t >> 2, qt = t & 3;
  {
    size_t base = ((size_t)w_ * 64 + n) * 1536 + head * 32 + qt * 8;
    uint4 qa = *(const uint4*)&qkv[base];
    uint4 ka = *(const uint4*)&qkv[base + 512];
    uint4 va = *(const uint4*)&qkv[base + 1024];
    int d = qt * 8;
    unpack8(qa, &qs[n][d], 0.17677669529663687f);  // HD^-0.5
    unpack8(ka, &ks[n][d], 1.0f);
    unpack8(va, &vs[n][d], 1.0f);
  }
  __syncthreads();

  float qr[32];
#pragma unroll
  for (int d = 0; d < 32; d++) qr[d] = qs[n][d];

  const int i1 = n >> 3, j1 = n & 7;
  const int h1 = wh * 8 + i1, w1 = wwi * 8 + j1;
  const int r1 = ((h1 < 24) ? 0 : ((h1 < 28) ? 1 : 2)) * 3 +
                 ((w1 < 24) ? 0 : ((w1 < 28) ? 1 : 2));
  float sv[16];
#pragma unroll
  for (int mi = 0; mi < 16; mi++) {
    int m = qt * 16 + mi;
    float a = 0.f;
#pragma unroll
    for (int d = 0; d < 32; d++) a += qr[d] * ks[m][d];
    int i2 = m >> 3, j2 = m & 7;
    a += rpb[((i1 - i2 + 7) * 15 + (j1 - j2 + 7)) * 16 + head];
    int h2 = wh * 8 + i2, w2 = wwi * 8 + j2;
    int r2 = ((h2 < 24) ? 0 : ((h2 < 28) ? 1 : 2)) * 3 +
             ((w2 < 24) ? 0 : ((w2 < 28) ? 1 : 2));
    if (r2 != r1) a -= 100.f;
    sv[mi] = a;
  }
  float mx = sv[0];
#pragma unroll
  for (int mi = 1; mi < 16; mi++) mx = fmaxf(mx, sv[mi]);
  mx = fmaxf(mx, __shfl_xor(mx, 1));
  mx = fmaxf(mx, __shfl_xor(mx, 2));
  float sum = 0.f;
#pragma unroll
  for (int mi = 0; mi < 16; mi++) { sv[mi] = __expf(sv[mi] - mx); sum += sv[mi]; }
  sum += __shfl_xor(sum, 1);
  sum += __shfl_xor(sum, 2);
  float inv = 1.f / sum;
#pragma unroll
  for (int mi = 0; mi < 16; mi++) ps[n][qt * 16 + mi] = sv[mi] * inv;
  __syncthreads();

  float acc8[8] = {0.f, 0.f, 0.f, 0.f, 0.f, 0.f, 0.f, 0.f};
  const int d0 = qt * 8;
  for (int m = 0; m < 64; m++) {
    float p = ps[n][m];
#pragma unroll
    for (int dd = 0; dd < 8; dd++) acc8[dd] += p * vs[m][d0 + dd];
  }
  size_t ob = ((size_t)w_ * 64 + n) * 512 + head * 32 + d0;
  uint4 o;
  o.x = (unsigned)f2bf(acc8[0]) | ((unsigned)f2bf(acc8[1]) << 16);
  o.y = (unsigned)f2bf(acc8[2]) | ((unsigned)f2bf(acc8[3]) << 16);
  o.z = (unsigned)f2bf(acc8[4]) | ((unsigned)f2bf(acc8[5]) << 16);
  o.w = (unsigned)f2bf(acc8[6]) | ((unsigned)f2bf(acc8[7]) << 16);
  *(uint4*)&out[ob] = o;
}

// ---------- launch ----------
extern "C" void kernel_launch(void* const* d_in, const int* in_sizes, int n_in,
                              void* d_out, int out_size, void* d_ws, size_t ws_size,
                              hipStream_t stream) {
  const float* x      = (const float*)d_in[0];
  const float* cond   = (const float*)d_in[1];
  const float* n1w    = (const float*)d_in[2];
  const float* n1b    = (const float*)d_in[3];
  const float* qkv_w  = (const float*)d_in[4];
  const float* qkv_b  = (const float*)d_in[5];
  const float* rpb    = (const float*)d_in[6];
  const float* proj_w = (const float*)d_in[7];
  const float* proj_b = (const float*)d_in[8];
  const float* n2w    = (const float*)d_in[9];
  const float* n2b    = (const float*)d_in[10];
  const float* fc1_w  = (const float*)d_in[11];
  const float* fc1_b  = (const float*)d_in[12];
  const float* fc2_w  = (const float*)d_in[13];
  const float* fc2_b  = (const float*)d_in[14];
  const float* ada_w  = (const float*)d_in[15];
  const float* ada_b  = (const float*)d_in[16];
  float* out = (float*)d_out;
  char* ws = (char*)d_ws;

  // workspace layout (bytes)
  u16*  qkvw_bf = (u16*)(ws + 0);            // 1,572,864
  u16*  projw_bf = (u16*)(ws + 1572864);     //   524,288
  u16*  fc1w_bf = (u16*)(ws + 2097152);      // 2,097,152
  u16*  fc2w_bf = (u16*)(ws + 4194304);      // 2,097,152
  float* ada    = (float*)(ws + 6291456);    //   393,216
  u16*  hw      = (u16*)(ws + 6684672);      // 33,554,432 (LN1 out; reused for LN2 out)
  u16*  qkvo    = (u16*)(ws + 40239104);     // 100,663,296
  u16*  attno   = (u16*)(ws + 140902400);    // 33,554,432
  u16*  mlp     = (u16*)(ws + 40239104);     // 134,217,728 (reuses qkvo+attno, both dead)
  // total 174,456,832 bytes

  convert_bf16<<<768, 256, 0, stream>>>(qkv_w, qkvw_bf, 196608);
  convert_bf16<<<256, 256, 0, stream>>>(proj_w, projw_bf, 65536);
  convert_bf16<<<1024, 256, 0, stream>>>(fc1_w, fc1w_bf, 262144);
  convert_bf16<<<1024, 256, 0, stream>>>(fc2_w, fc2w_bf, 262144);

  ada_kernel<<<dim3(12, 32), 256, 0, stream>>>(cond, ada_w, ada_b, ada);
  ln_mod<0><<<32768, 128, 0, stream>>>(x, ada, n1w, n1b, hw);
  gemm_bf16<0><<<dim3(12, 256), 256, 0, stream>>>(hw, qkvw_bf, qkv_b, 512, 1536,
                                                  qkvo, nullptr, nullptr, nullptr);
  attn_kernel<<<8192, 256, 0, stream>>>(qkvo, rpb, attno);
  gemm_bf16<2><<<dim3(4, 256), 256, 0, stream>>>(attno, projw_bf, proj_b, 512, 512,
                                                 nullptr, out, x, ada);
  ln_mod<1><<<32768, 128, 0, stream>>>(out, ada, n2w, n2b, hw);
  gemm_bf16<1><<<dim3(16, 256), 256, 0, stream>>>(hw, fc1w_bf, fc1_b, 512, 2048,
                                                  mlp, nullptr, nullptr, nullptr);
  gemm_bf16<3><<<dim3(4, 256), 256, 0, stream>>>(mlp, fc2w_bf, fc2_b, 2048, 512,
                                                 nullptr, out, nullptr, ada);
}

// Round 2
// 618.026 us; speedup vs baseline: 1.2108x; 1.2108x over previous
//
#include <hip/hip_runtime.h>
#include <math.h>

typedef unsigned short u16;
typedef short short8 __attribute__((ext_vector_type(8)));
typedef float floatx4 __attribute__((ext_vector_type(4)));

#define SS 4
#define C_DIM 512
#define L_TOK 1024   // H*W

// ---------- helpers ----------
static __device__ __forceinline__ u16 f2bf(float f) {
  union { float f; unsigned u; } v; v.f = f;
  unsigned u = v.u;
  unsigned r = (u + 0x7fffu + ((u >> 16) & 1u)) >> 16;  // RNE
  return (u16)r;
}

typedef const __attribute__((address_space(1))) void* gvp;
typedef __attribute__((address_space(3))) void* lvp;
#define ASYNC16(g, l) __builtin_amdgcn_global_load_lds((gvp)(g), (lvp)(l), 16, 0, 0)

// ---------- fp32 -> bf16 weight conversion ----------
__global__ __launch_bounds__(256) void convert_bf16(const float* __restrict__ src,
                                                    u16* __restrict__ dst, int n4) {
  int i = blockIdx.x * 256 + threadIdx.x;
  if (i >= n4) return;
  float4 v = ((const float4*)src)[i];
  ushort4 o;
  o.x = f2bf(v.x); o.y = f2bf(v.y); o.z = f2bf(v.z); o.w = f2bf(v.w);
  ((ushort4*)dst)[i] = o;
}

// ---------- ada = silu(cond) @ ada_w.T + ada_b  [32, 3072] ----------
__global__ __launch_bounds__(256) void ada_kernel(const float* __restrict__ cond,
                                                  const float* __restrict__ w,
                                                  const float* __restrict__ bias,
                                                  float* __restrict__ ada) {
  int b = blockIdx.y;
  int j = blockIdx.x * 256 + threadIdx.x;   // < 3072
  __shared__ float sc[C_DIM];
  for (int c = threadIdx.x; c < C_DIM; c += 256) {
    float v = cond[b * C_DIM + c];
    sc[c] = v / (1.0f + expf(-v));
  }
  __syncthreads();
  const float* wr = w + (size_t)j * C_DIM;
  float acc = 0.f;
  for (int k = 0; k < C_DIM; k += 4) {
    float4 wv = *(const float4*)&wr[k];
    acc += sc[k] * wv.x + sc[k + 1] * wv.y + sc[k + 2] * wv.z + sc[k + 3] * wv.w;
  }
  ada[(size_t)b * 3072 + j] = acc + bias[j];
}

// ---------- rpbT[head][q][k] + per-window mask bitwords ----------
__global__ __launch_bounds__(64) void prep_attn(const float* __restrict__ rpb,
                                                float* __restrict__ rpbT,
                                                unsigned long long* __restrict__ maskbits) {
  int q = blockIdx.x;        // 64
  int head = blockIdx.y;     // 16
  int k = threadIdx.x;       // 64
  int i1 = q >> 3, j1 = q & 7, i2 = k >> 3, j2 = k & 7;
  rpbT[((size_t)head * 64 + q) * 64 + k] =
      rpb[((i1 - i2 + 7) * 15 + (j1 - j2 + 7)) * 16 + head];
  if (head == 0) {
    for (int widx = 0; widx < 16; widx++) {
      int wh = widx >> 2, wwi = widx & 3;
      int iq = q >> 3, jq = q & 7, ik = k >> 3, jk = k & 7;
      int hq = wh * 8 + iq, wq = wwi * 8 + jq;
      int hk = wh * 8 + ik, wk = wwi * 8 + jk;
      int rq = ((hq < 24) ? 0 : (hq < 28) ? 1 : 2) * 3 + ((wq < 24) ? 0 : (wq < 28) ? 1 : 2);
      int rk = ((hk < 24) ? 0 : (hk < 28) ? 1 : 2) * 3 + ((wk < 24) ? 0 : (wk < 28) ? 1 : 2);
      unsigned long long m = __ballot(rq != rk);
      if (k == 0) maskbits[widx * 64 + q] = m;
    }
  }
}

// ---------- LN + modulate (+ optional roll/window gather), output bf16 ----------
template <int MODE>
__global__ __launch_bounds__(128) void ln_mod(const float* __restrict__ x,
                                              const float* __restrict__ ada,
                                              const float* __restrict__ nw,
                                              const float* __restrict__ nb,
                                              u16* __restrict__ out) {
  int m = blockIdx.x;           // output row (window layout for MODE 0)
  int b = m >> 10;
  size_t srow;
  if (MODE == 0) {
    int n = m & 63, widx = (m >> 6) & 15;
    int wh = widx >> 2, wwi = widx & 3;
    int i = n >> 3, j = n & 7;
    int hs = (wh * 8 + i + SS) & 31;
    int ws_ = (wwi * 8 + j + SS) & 31;
    srow = (size_t)b * L_TOK + hs * 32 + ws_;
  } else {
    srow = (size_t)m;
  }
  const float* src = x + srow * C_DIM;
  int t = threadIdx.x;
  float4 v = *(const float4*)&src[t * 4];
  float s = v.x + v.y + v.z + v.w;
  float ss = v.x * v.x + v.y * v.y + v.z * v.z + v.w * v.w;
#pragma unroll
  for (int off = 32; off > 0; off >>= 1) {
    s += __shfl_down(s, off);
    ss += __shfl_down(ss, off);
  }
  __shared__ float red[4];
  if ((t & 63) == 0) { red[(t >> 6) * 2] = s; red[(t >> 6) * 2 + 1] = ss; }
  __syncthreads();
  float mean = (red[0] + red[2]) * (1.f / C_DIM);
  float var = (red[1] + red[3]) * (1.f / C_DIM) - mean * mean;
  float rstd = rsqrtf(var + 1e-5f);
  const float* sh = ada + (size_t)b * 3072 + (MODE ? 1536 : 0);
  const float* scm = ada + (size_t)b * 3072 + (MODE ? 2048 : 512);
  int c = t * 4;
  ushort4 o;
  {
    float y;
    y = ((v.x - mean) * rstd * nw[c + 0] + nb[c + 0]) * (1.f + scm[c + 0]) + sh[c + 0]; o.x = f2bf(y);
    y = ((v.y - mean) * rstd * nw[c + 1] + nb[c + 1]) * (1.f + scm[c + 1]) + sh[c + 1]; o.y = f2bf(y);
    y = ((v.z - mean) * rstd * nw[c + 2] + nb[c + 2]) * (1.f + scm[c + 2]) + sh[c + 2]; o.z = f2bf(y);
    y = ((v.w - mean) * rstd * nw[c + 3] + nb[c + 3]) * (1.f + scm[c + 3]) + sh[c + 3]; o.w = f2bf(y);
  }
  *(ushort4*)&out[(size_t)m * C_DIM + c] = o;
}

// ---------- bf16 MFMA GEMM: out[M,N] = A[M,K] @ Bw[N,K]^T + bias ----------
// EPI 0: bias -> bf16             (qkv)
// EPI 1: bias, exact GELU -> bf16 (fc1)
// EPI 2: bias, window-reverse + roll scatter, x + g_msa*v -> fp32 d_out (proj)
// EPI 3: bias, d_out += g_mlp*v in place (fc2)
template <int EPI>
__global__ __launch_bounds__(256, 2) void gemm_bf16(
    const u16* __restrict__ A, const u16* __restrict__ Bw,
    const float* __restrict__ bias, int K, int N,
    u16* __restrict__ outBf, float* __restrict__ outF,
    const float* __restrict__ resid, const float* __restrict__ ada) {
  __shared__ __align__(16) u16 lA[128 * 32];
  __shared__ __align__(16) u16 lB[128 * 32];
  const int tid = threadIdx.x;
  const int lane = tid & 63, wave = tid >> 6;
  const int wr = wave >> 1, wc = wave & 1;
  const int rowA0 = blockIdx.y * 128;
  const int colB0 = blockIdx.x * 128;
  floatx4 acc[4][4];
#pragma unroll
  for (int a = 0; a < 4; a++)
#pragma unroll
    for (int b = 0; b < 4; b++) acc[a][b] = (floatx4){0.f, 0.f, 0.f, 0.f};

  const int r0 = tid >> 2, c0 = (tid & 3) * 8;  // staging chunk (16B = 8 bf16)
  const int r1 = r0 + 64;
  const int q = lane >> 4, fr = lane & 15;

  const u16* gA0 = &A[(size_t)(rowA0 + r0) * K + c0];
  const u16* gA1 = &A[(size_t)(rowA0 + r1) * K + c0];
  const u16* gB0 = &Bw[(size_t)(colB0 + r0) * K + c0];
  const u16* gB1 = &Bw[(size_t)(colB0 + r1) * K + c0];
  // async global->LDS: HW writes lane's 16B at ldsbase + lane*16; our layout is
  // byte offset tid*16 (= wave*1024 + lane*16) for chunk0, +4096 for chunk1.
  u16* lA0 = &lA[wave * 512];
  u16* lA1 = &lA[2048 + wave * 512];
  u16* lB0 = &lB[wave * 512];
  u16* lB1 = &lB[2048 + wave * 512];

  for (int k0 = 0; k0 < K; k0 += 32) {
    ASYNC16(gA0 + k0, lA0);
    ASYNC16(gA1 + k0, lA1);
    ASYNC16(gB0 + k0, lB0);
    ASYNC16(gB1 + k0, lB1);
    __syncthreads();
    short8 af[4], bfr[4];
#pragma unroll
    for (int mi = 0; mi < 4; mi++)
      af[mi] = *(const short8*)&lA[(wr * 64 + mi * 16 + fr) * 32 + q * 8];
#pragma unroll
    for (int ni = 0; ni < 4; ni++)
      bfr[ni] = *(const short8*)&lB[(wc * 64 + ni * 16 + fr) * 32 + q * 8];
#pragma unroll
    for (int mi = 0; mi < 4; mi++)
#pragma unroll
      for (int ni = 0; ni < 4; ni++)
        acc[mi][ni] = __builtin_amdgcn_mfma_f32_16x16x32_bf16(af[mi], bfr[ni], acc[mi][ni], 0, 0, 0);
    __syncthreads();
  }

#pragma unroll
  for (int mi = 0; mi < 4; mi++) {
#pragma unroll
    for (int ni = 0; ni < 4; ni++) {
      int col = colB0 + wc * 64 + ni * 16 + fr;
      float bv = bias[col];
#pragma unroll
      for (int r = 0; r < 4; r++) {
        int row = rowA0 + wr * 64 + mi * 16 + q * 4 + r;
        float v = acc[mi][ni][r] + bv;
        if (EPI == 0) {
          outBf[(size_t)row * N + col] = f2bf(v);
        } else if (EPI == 1) {
          v = 0.5f * v * (1.f + erff(v * 0.70710678118654752f));
          outBf[(size_t)row * N + col] = f2bf(v);
        } else if (EPI == 2) {
          int b = row >> 10;
          int n = row & 63, widx = (row >> 6) & 15;
          int wh = widx >> 2, wwi = widx & 3;
          int i = n >> 3, j = n & 7;
          int hd = (wh * 8 + i + SS) & 31;
          int wd = (wwi * 8 + j + SS) & 31;
          size_t dst = ((size_t)b * L_TOK + hd * 32 + wd) * C_DIM + col;
          outF[dst] = resid[dst] + ada[(size_t)b * 3072 + 1024 + col] * v;
        } else {
          int b = row >> 10;
          size_t dst = (size_t)row * C_DIM + col;
          outF[dst] = outF[dst] + ada[(size_t)b * 3072 + 2560 + col] * v;
        }
      }
    }
  }
}

// ---------- MFMA windowed attention: one WAVE per (window, head) ----------
// S^T = K·Q^T via mfma (A=K rows, B=Q rows, both direct-from-global 16B frags)
// softmax in registers (cross-quad shfl), P -> LDS bf16, O^T = V^T·P^T via mfma.
__global__ __launch_bounds__(256, 2) void attn_mfma(const u16* __restrict__ qkv,
                                                    const float* __restrict__ rpbT,
                                                    const unsigned long long* __restrict__ maskbits,
                                                    u16* __restrict__ out) {
  __shared__ __align__(16) u16 sVT[4][32 * 72];  // V^T per wave, stride 72
  __shared__ __align__(16) u16 sP[4][64 * 72];   // P  per wave, stride 72
  const int tid = threadIdx.x, wave = tid >> 6, lane = tid & 63;
  const int col = lane & 15, quad = lane >> 4;
  const int id = blockIdx.x * 4 + wave;          // window-head id
  const int w_ = id >> 4, head = id & 15;
  const int widx = w_ & 15;
  u16* VT = sVT[wave];
  u16* P = sP[wave];
  const u16* base = qkv + (size_t)w_ * 64 * 1536 + head * 32;

  // stage V^T (transpose): lane handles token = lane, 32 channels
  {
    const u16* vrow = base + 1024 + (size_t)lane * 1536;
#pragma unroll
    for (int c = 0; c < 4; c++) {
      uint4 u = *(const uint4*)&vrow[c * 8];
      unsigned uu0 = u.x, uu1 = u.y, uu2 = u.z, uu3 = u.w;
      VT[(c * 8 + 0) * 72 + lane] = (u16)(uu0 & 0xffff);
      VT[(c * 8 + 1) * 72 + lane] = (u16)(uu0 >> 16);
      VT[(c * 8 + 2) * 72 + lane] = (u16)(uu1 & 0xffff);
      VT[(c * 8 + 3) * 72 + lane] = (u16)(uu1 >> 16);
      VT[(c * 8 + 4) * 72 + lane] = (u16)(uu2 & 0xffff);
      VT[(c * 8 + 5) * 72 + lane] = (u16)(uu2 >> 16);
      VT[(c * 8 + 6) * 72 + lane] = (u16)(uu3 & 0xffff);
      VT[(c * 8 + 7) * 72 + lane] = (u16)(uu3 >> 16);
    }
  }

  // K (A-op) and Q (B-op) fragments straight from global: 16B contiguous/lane
  short8 kf[4], qf[4];
#pragma unroll
  for (int mi = 0; mi < 4; mi++)
    kf[mi] = *(const short8*)(base + 512 + (size_t)(mi * 16 + col) * 1536 + quad * 8);
#pragma unroll
  for (int ni = 0; ni < 4; ni++)
    qf[ni] = *(const short8*)(base + (size_t)(ni * 16 + col) * 1536 + quad * 8);

  floatx4 st[4][4];
#pragma unroll
  for (int mi = 0; mi < 4; mi++)
#pragma unroll
    for (int ni = 0; ni < 4; ni++) st[mi][ni] = (floatx4){0.f, 0.f, 0.f, 0.f};
#pragma unroll
  for (int mi = 0; mi < 4; mi++)
#pragma unroll
    for (int ni = 0; ni < 4; ni++)
      st[mi][ni] = __builtin_amdgcn_mfma_f32_16x16x32_bf16(kf[mi], qf[ni], st[mi][ni], 0, 0, 0);
  // st[mi][ni][r] = S^T[key = mi*16+quad*4+r][q = ni*16+col]

  const float scale = 0.17677669529663687f;  // 32^-0.5
  float invq[4];
#pragma unroll
  for (int ni = 0; ni < 4; ni++) {
    int q = ni * 16 + col;
    unsigned long long mw = maskbits[widx * 64 + q];
    const float* rp = rpbT + ((size_t)head * 64 + q) * 64;
    float mx = -1e30f;
#pragma unroll
    for (int mi = 0; mi < 4; mi++) {
      floatx4 r4 = *(const floatx4*)&rp[mi * 16 + quad * 4];
#pragma unroll
      for (int r = 0; r < 4; r++) {
        int key = mi * 16 + quad * 4 + r;
        float s = st[mi][ni][r] * scale + r4[r];
        s -= ((mw >> key) & 1ull) ? 100.f : 0.f;
        st[mi][ni][r] = s;
        mx = fmaxf(mx, s);
      }
    }
    mx = fmaxf(mx, __shfl_xor(mx, 16));
    mx = fmaxf(mx, __shfl_xor(mx, 32));
    float sum = 0.f;
#pragma unroll
    for (int mi = 0; mi < 4; mi++) {
      float e0 = __expf(st[mi][ni][0] - mx);
      float e1 = __expf(st[mi][ni][1] - mx);
      float e2 = __expf(st[mi][ni][2] - mx);
      float e3 = __expf(st[mi][ni][3] - mx);
      sum += e0 + e1 + e2 + e3;
      ushort4 pk;
      pk.x = f2bf(e0); pk.y = f2bf(e1); pk.z = f2bf(e2); pk.w = f2bf(e3);
      *(ushort4*)&P[q * 72 + mi * 16 + quad * 4] = pk;  // P[q][key] (unnormalized)
    }
    sum += __shfl_xor(sum, 16);
    sum += __shfl_xor(sum, 32);
    invq[ni] = 1.f / sum;
  }

  // O^T = V^T · P^T : A = V^T rows (d), B = P rows (q); K=64 in 2 chunks
  floatx4 o[2][4];
#pragma unroll
  for (int mt = 0; mt < 2; mt++)
#pragma unroll
    for (int nt = 0; nt < 4; nt++) o[mt][nt] = (floatx4){0.f, 0.f, 0.f, 0.f};
#pragma unroll
  for (int kc = 0; kc < 2; kc++) {
    short8 vf0 = *(const short8*)&VT[(col) * 72 + kc * 32 + quad * 8];
    short8 vf1 = *(const short8*)&VT[(16 + col) * 72 + kc * 32 + quad * 8];
#pragma unroll
    for (int nt = 0; nt < 4; nt++) {
      short8 pf = *(const short8*)&P[(nt * 16 + col) * 72 + kc * 32 + quad * 8];
      o[0][nt] = __builtin_amdgcn_mfma_f32_16x16x32_bf16(vf0, pf, o[0][nt], 0, 0, 0);
      o[1][nt] = __builtin_amdgcn_mfma_f32_16x16x32_bf16(vf1, pf, o[1][nt], 0, 0, 0);
    }
  }

  // write O: o[mt][nt][r] = O[q = nt*16+col][d = mt*16+quad*4+r] (pre-scale)
#pragma unroll
  for (int mt = 0; mt < 2; mt++)
#pragma unroll
    for (int nt = 0; nt < 4; nt++) {
      int q = nt * 16 + col;
      float iv = invq[nt];
      ushort4 pk;
      pk.x = f2bf(o[mt][nt][0] * iv);
      pk.y = f2bf(o[mt][nt][1] * iv);
      pk.z = f2bf(o[mt][nt][2] * iv);
      pk.w = f2bf(o[mt][nt][3] * iv);
      *(ushort4*)&out[((size_t)w_ * 64 + q) * 512 + head * 32 + mt * 16 + quad * 4] = pk;
    }
}

// ---------- launch ----------
extern "C" void kernel_launch(void* const* d_in, const int* in_sizes, int n_in,
                              void* d_out, int out_size, void* d_ws, size_t ws_size,
                              hipStream_t stream) {
  const float* x      = (const float*)d_in[0];
  const float* cond   = (const float*)d_in[1];
  const float* n1w    = (const float*)d_in[2];
  const float* n1b    = (const float*)d_in[3];
  const float* qkv_w  = (const float*)d_in[4];
  const float* qkv_b  = (const float*)d_in[5];
  const float* rpb    = (const float*)d_in[6];
  const float* proj_w = (const float*)d_in[7];
  const float* proj_b = (const float*)d_in[8];
  const float* n2w    = (const float*)d_in[9];
  const float* n2b    = (const float*)d_in[10];
  const float* fc1_w  = (const float*)d_in[11];
  const float* fc1_b  = (const float*)d_in[12];
  const float* fc2_w  = (const float*)d_in[13];
  const float* fc2_b  = (const float*)d_in[14];
  const float* ada_w  = (const float*)d_in[15];
  const float* ada_b  = (const float*)d_in[16];
  float* out = (float*)d_out;
  char* ws = (char*)d_ws;

  // workspace layout (bytes)
  u16*  qkvw_bf  = (u16*)(ws + 0);              // 1,572,864
  u16*  projw_bf = (u16*)(ws + 1572864);        //   524,288
  u16*  fc1w_bf  = (u16*)(ws + 2097152);        // 2,097,152
  u16*  fc2w_bf  = (u16*)(ws + 4194304);        // 2,097,152
  float* ada     = (float*)(ws + 6291456);      //   393,216
  float* rpbT    = (float*)(ws + 6684672);      //   262,144
  unsigned long long* maskb = (unsigned long long*)(ws + 6946816);  // 8,192
  u16*  hw       = (u16*)(ws + 6955008);        // 33,554,432
  u16*  qkvo     = (u16*)(ws + 40509440);       // 100,663,296
  u16*  attno    = (u16*)(ws + 141172736);      // 33,554,432
  u16*  mlp      = (u16*)(ws + 40509440);       // 134,217,728 (reuses qkvo+attno)
  // total 174,727,168 bytes

  convert_bf16<<<768, 256, 0, stream>>>(qkv_w, qkvw_bf, 196608);
  convert_bf16<<<256, 256, 0, stream>>>(proj_w, projw_bf, 65536);
  convert_bf16<<<1024, 256, 0, stream>>>(fc1_w, fc1w_bf, 262144);
  convert_bf16<<<1024, 256, 0, stream>>>(fc2_w, fc2w_bf, 262144);
  prep_attn<<<dim3(64, 16), 64, 0, stream>>>(rpb, rpbT, maskb);

  ada_kernel<<<dim3(12, 32), 256, 0, stream>>>(cond, ada_w, ada_b, ada);
  ln_mod<0><<<32768, 128, 0, stream>>>(x, ada, n1w, n1b, hw);
  gemm_bf16<0><<<dim3(12, 256), 256, 0, stream>>>(hw, qkvw_bf, qkv_b, 512, 1536,
                                                  qkvo, nullptr, nullptr, nullptr);
  attn_mfma<<<2048, 256, 0, stream>>>(qkvo, rpbT, maskb, attno);
  gemm_bf16<2><<<dim3(4, 256), 256, 0, stream>>>(attno, projw_bf, proj_b, 512, 512,
                                                 nullptr, out, x, ada);
  ln_mod<1><<<32768, 128, 0, stream>>>(out, ada, n2w, n2b, hw);
  gemm_bf16<1><<<dim3(16, 256), 256, 0, stream>>>(hw, fc1w_bf, fc1_b, 512, 2048,
                                                  mlp, nullptr, nullptr, nullptr);
  gemm_bf16<3><<<dim3(4, 256), 256, 0, stream>>>(mlp, fc2w_bf, fc2_b, 2048, 512,
                                                 nullptr, out, nullptr, ada);
}

// Round 3
// 592.754 us; speedup vs baseline: 1.2624x; 1.0426x over previous
//
#include <hip/hip_runtime.h>
#include <math.h>

typedef unsigned short u16;
typedef short short8 __attribute__((ext_vector_type(8)));
typedef float floatx4 __attribute__((ext_vector_type(4)));

#define SS 4
#define C_DIM 512
#define L_TOK 1024   // H*W

// ---------- helpers ----------
static __device__ __forceinline__ u16 f2bf(float f) {
  union { float f; unsigned u; } v; v.f = f;
  unsigned u = v.u;
  unsigned r = (u + 0x7fffu + ((u >> 16) & 1u)) >> 16;  // RNE
  return (u16)r;
}

typedef const __attribute__((address_space(1))) void* gvp;
typedef __attribute__((address_space(3))) void* lvp;
#define ASYNC16(g, l) __builtin_amdgcn_global_load_lds((gvp)(g), (lvp)(l), 16, 0, 0)

// ---------- fp32 -> bf16 weight conversion ----------
__global__ __launch_bounds__(256) void convert_bf16(const float* __restrict__ src,
                                                    u16* __restrict__ dst, int n4) {
  int i = blockIdx.x * 256 + threadIdx.x;
  if (i >= n4) return;
  float4 v = ((const float4*)src)[i];
  ushort4 o;
  o.x = f2bf(v.x); o.y = f2bf(v.y); o.z = f2bf(v.z); o.w = f2bf(v.w);
  ((ushort4*)dst)[i] = o;
}

// ---------- ada = silu(cond) @ ada_w.T + ada_b  [32, 3072] ----------
__global__ __launch_bounds__(256) void ada_kernel(const float* __restrict__ cond,
                                                  const float* __restrict__ w,
                                                  const float* __restrict__ bias,
                                                  float* __restrict__ ada) {
  int b = blockIdx.y;
  int j = blockIdx.x * 256 + threadIdx.x;   // < 3072
  __shared__ float sc[C_DIM];
  for (int c = threadIdx.x; c < C_DIM; c += 256) {
    float v = cond[b * C_DIM + c];
    sc[c] = v / (1.0f + expf(-v));
  }
  __syncthreads();
  const float* wr = w + (size_t)j * C_DIM;
  float acc = 0.f;
  for (int k = 0; k < C_DIM; k += 4) {
    float4 wv = *(const float4*)&wr[k];
    acc += sc[k] * wv.x + sc[k + 1] * wv.y + sc[k + 2] * wv.z + sc[k + 3] * wv.w;
  }
  ada[(size_t)b * 3072 + j] = acc + bias[j];
}

// ---------- rpbT[head][q][k] + per-window mask bitwords ----------
__global__ __launch_bounds__(64) void prep_attn(const float* __restrict__ rpb,
                                                float* __restrict__ rpbT,
                                                unsigned long long* __restrict__ maskbits) {
  int q = blockIdx.x;        // 64
  int head = blockIdx.y;     // 16
  int k = threadIdx.x;       // 64
  int i1 = q >> 3, j1 = q & 7, i2 = k >> 3, j2 = k & 7;
  rpbT[((size_t)head * 64 + q) * 64 + k] =
      rpb[((i1 - i2 + 7) * 15 + (j1 - j2 + 7)) * 16 + head];
  if (head == 0) {
    for (int widx = 0; widx < 16; widx++) {
      int wh = widx >> 2, wwi = widx & 3;
      int hq = wh * 8 + i1, wq = wwi * 8 + j1;
      int hk = wh * 8 + i2, wk = wwi * 8 + j2;
      int rq = ((hq < 24) ? 0 : (hq < 28) ? 1 : 2) * 3 + ((wq < 24) ? 0 : (wq < 28) ? 1 : 2);
      int rk = ((hk < 24) ? 0 : (hk < 28) ? 1 : 2) * 3 + ((wk < 24) ? 0 : (wk < 28) ? 1 : 2);
      unsigned long long m = __ballot(rq != rk);
      if (k == 0) maskbits[widx * 64 + q] = m;
    }
  }
}

// ---------- LN + modulate (+ optional roll/window gather), output bf16 ----------
template <int MODE>
__global__ __launch_bounds__(128) void ln_mod(const float* __restrict__ x,
                                              const float* __restrict__ ada,
                                              const float* __restrict__ nw,
                                              const float* __restrict__ nb,
                                              u16* __restrict__ out) {
  int m = blockIdx.x;           // output row (window layout for MODE 0)
  int b = m >> 10;
  size_t srow;
  if (MODE == 0) {
    int n = m & 63, widx = (m >> 6) & 15;
    int wh = widx >> 2, wwi = widx & 3;
    int i = n >> 3, j = n & 7;
    int hs = (wh * 8 + i + SS) & 31;
    int ws_ = (wwi * 8 + j + SS) & 31;
    srow = (size_t)b * L_TOK + hs * 32 + ws_;
  } else {
    srow = (size_t)m;
  }
  const float* src = x + srow * C_DIM;
  int t = threadIdx.x;
  float4 v = *(const float4*)&src[t * 4];
  float s = v.x + v.y + v.z + v.w;
  float ss = v.x * v.x + v.y * v.y + v.z * v.z + v.w * v.w;
#pragma unroll
  for (int off = 32; off > 0; off >>= 1) {
    s += __shfl_down(s, off);
    ss += __shfl_down(ss, off);
  }
  __shared__ float red[4];
  if ((t & 63) == 0) { red[(t >> 6) * 2] = s; red[(t >> 6) * 2 + 1] = ss; }
  __syncthreads();
  float mean = (red[0] + red[2]) * (1.f / C_DIM);
  float var = (red[1] + red[3]) * (1.f / C_DIM) - mean * mean;
  float rstd = rsqrtf(var + 1e-5f);
  const float* sh = ada + (size_t)b * 3072 + (MODE ? 1536 : 0);
  const float* scm = ada + (size_t)b * 3072 + (MODE ? 2048 : 512);
  int c = t * 4;
  ushort4 o;
  {
    float y;
    y = ((v.x - mean) * rstd * nw[c + 0] + nb[c + 0]) * (1.f + scm[c + 0]) + sh[c + 0]; o.x = f2bf(y);
    y = ((v.y - mean) * rstd * nw[c + 1] + nb[c + 1]) * (1.f + scm[c + 1]) + sh[c + 1]; o.y = f2bf(y);
    y = ((v.z - mean) * rstd * nw[c + 2] + nb[c + 2]) * (1.f + scm[c + 2]) + sh[c + 2]; o.z = f2bf(y);
    y = ((v.w - mean) * rstd * nw[c + 3] + nb[c + 3]) * (1.f + scm[c + 3]) + sh[c + 3]; o.w = f2bf(y);
  }
  *(ushort4*)&out[(size_t)m * C_DIM + c] = o;
}

// ---------- bf16 MFMA GEMM: out[M,N] = A[M,K] @ Bw[N,K]^T + bias ----------
// C^T register layout: mfma(a=W-frag, b=X-frag) so each lane holds 4
// consecutive output COLUMNS -> packed 8B/16B epilogue stores.
// EPI 0: bias -> bf16             (qkv)
// EPI 1: bias, tanh-GELU -> bf16  (fc1)
// EPI 2: bias, window-reverse + roll scatter, x + g_msa*v -> fp32 d_out (proj)
// EPI 3: bias, d_out += g_mlp*v in place (fc2)
template <int EPI>
__global__ __launch_bounds__(256, 2) void gemm_bf16(
    const u16* __restrict__ A, const u16* __restrict__ Bw,
    const float* __restrict__ bias, int K, int N,
    u16* __restrict__ outBf, float* __restrict__ outF,
    const float* __restrict__ resid, const float* __restrict__ ada) {
  // [kc][128 rows][32 cols], kc = which 32-wide k-chunk of the 64-wide tile
  __shared__ __align__(16) u16 lA[2][128 * 32];
  __shared__ __align__(16) u16 lB[2][128 * 32];
  const int tid = threadIdx.x;
  const int lane = tid & 63, wave = tid >> 6;
  const int wr = wave >> 1, wc = wave & 1;
  const int rowA0 = blockIdx.y * 128;
  const int colB0 = blockIdx.x * 128;
  floatx4 acc[4][4];
#pragma unroll
  for (int a = 0; a < 4; a++)
#pragma unroll
    for (int b = 0; b < 4; b++) acc[a][b] = (floatx4){0.f, 0.f, 0.f, 0.f};

  const int r0 = tid >> 2, c0 = (tid & 3) * 8;  // staging chunk (16B = 8 bf16)
  const int q = lane >> 4, fr = lane & 15;

  const u16* gA = &A[(size_t)(rowA0 + r0) * K + c0];
  const u16* gB = &Bw[(size_t)(colB0 + r0) * K + c0];
  const size_t up = (size_t)64 * K;  // row-half stride in global
  // async global->LDS: HW writes lane's 16B at ldsbase + lane*16.
  // chunk layout: [kc]*4096 + [rowhalf]*2048 + wave*512 (u16 units)
  u16* lA0 = &lA[0][wave * 512];
  u16* lB0 = &lB[0][wave * 512];

  for (int k0 = 0; k0 < K; k0 += 64) {
    ASYNC16(gA + k0, lA0);
    ASYNC16(gA + k0 + up, lA0 + 2048);
    ASYNC16(gA + k0 + 32, lA0 + 4096);
    ASYNC16(gA + k0 + 32 + up, lA0 + 6144);
    ASYNC16(gB + k0, lB0);
    ASYNC16(gB + k0 + up, lB0 + 2048);
    ASYNC16(gB + k0 + 32, lB0 + 4096);
    ASYNC16(gB + k0 + 32 + up, lB0 + 6144);
    __syncthreads();
#pragma unroll
    for (int kc = 0; kc < 2; kc++) {
      short8 xf[4], wf[4];
#pragma unroll
      for (int mi = 0; mi < 4; mi++)
        xf[mi] = *(const short8*)&lA[kc][(wr * 64 + mi * 16 + fr) * 32 + q * 8];
#pragma unroll
      for (int ni = 0; ni < 4; ni++)
        wf[ni] = *(const short8*)&lB[kc][(wc * 64 + ni * 16 + fr) * 32 + q * 8];
#pragma unroll
      for (int mi = 0; mi < 4; mi++)
#pragma unroll
        for (int ni = 0; ni < 4; ni++)
          acc[mi][ni] = __builtin_amdgcn_mfma_f32_16x16x32_bf16(wf[ni], xf[mi], acc[mi][ni], 0, 0, 0);
    }
    __syncthreads();
  }

  // acc[mi][ni][r]: C[row = rowA0+wr*64+mi*16+fr][col = colB0+wc*64+ni*16+q*4+r]
#pragma unroll
  for (int mi = 0; mi < 4; mi++) {
    int row = rowA0 + wr * 64 + mi * 16 + fr;
#pragma unroll
    for (int ni = 0; ni < 4; ni++) {
      int col0 = colB0 + wc * 64 + ni * 16 + q * 4;
      float4 bv = *(const float4*)&bias[col0];
      float v0 = acc[mi][ni][0] + bv.x;
      float v1 = acc[mi][ni][1] + bv.y;
      float v2 = acc[mi][ni][2] + bv.z;
      float v3 = acc[mi][ni][3] + bv.w;
      if (EPI == 1) {  // tanh-form GELU (max dev ~3e-4 << bf16 ulp here)
        v0 = __fdividef(v0, 1.f + __expf(-v0 * (1.59576912f + 0.07135481f * v0 * v0)));
        v1 = __fdividef(v1, 1.f + __expf(-v1 * (1.59576912f + 0.07135481f * v1 * v1)));
        v2 = __fdividef(v2, 1.f + __expf(-v2 * (1.59576912f + 0.07135481f * v2 * v2)));
        v3 = __fdividef(v3, 1.f + __expf(-v3 * (1.59576912f + 0.07135481f * v3 * v3)));
      }
      if (EPI == 0 || EPI == 1) {
        ushort4 pk;
        pk.x = f2bf(v0); pk.y = f2bf(v1); pk.z = f2bf(v2); pk.w = f2bf(v3);
        *(ushort4*)&outBf[(size_t)row * N + col0] = pk;
      } else if (EPI == 2) {
        int b = row >> 10;
        int n = row & 63, widx = (row >> 6) & 15;
        int wh = widx >> 2, wwi = widx & 3;
        int i = n >> 3, j = n & 7;
        int hd = (wh * 8 + i + SS) & 31;
        int wd = (wwi * 8 + j + SS) & 31;
        size_t dst = ((size_t)b * L_TOK + hd * 32 + wd) * C_DIM + col0;
        float4 rs = *(const float4*)&resid[dst];
        float4 g = *(const float4*)&ada[(size_t)b * 3072 + 1024 + col0];
        float4 o;
        o.x = rs.x + g.x * v0; o.y = rs.y + g.y * v1;
        o.z = rs.z + g.z * v2; o.w = rs.w + g.w * v3;
        *(float4*)&outF[dst] = o;
      } else {
        int b = row >> 10;
        size_t dst = (size_t)row * C_DIM + col0;
        float4 cur = *(const float4*)&outF[dst];
        float4 g = *(const float4*)&ada[(size_t)b * 3072 + 2560 + col0];
        float4 o;
        o.x = cur.x + g.x * v0; o.y = cur.y + g.y * v1;
        o.z = cur.z + g.z * v2; o.w = cur.w + g.w * v3;
        *(float4*)&outF[dst] = o;
      }
    }
  }
}

// ---------- MFMA windowed attention: one WAVE per (window, head) ----------
__global__ __launch_bounds__(256, 2) void attn_mfma(const u16* __restrict__ qkv,
                                                    const float* __restrict__ rpbT,
                                                    const unsigned long long* __restrict__ maskbits,
                                                    u16* __restrict__ out) {
  __shared__ __align__(16) u16 sVT[4][32 * 72];  // V^T per wave, stride 72
  __shared__ __align__(16) u16 sP[4][64 * 72];   // P  per wave, stride 72
  const int tid = threadIdx.x, wave = tid >> 6, lane = tid & 63;
  const int col = lane & 15, quad = lane >> 4;
  const int id = blockIdx.x * 4 + wave;          // window-head id
  const int w_ = id >> 4, head = id & 15;
  const int widx = w_ & 15;
  u16* VT = sVT[wave];
  u16* P = sP[wave];
  const u16* base = qkv + (size_t)w_ * 64 * 1536 + head * 32;

  {
    const u16* vrow = base + 1024 + (size_t)lane * 1536;
#pragma unroll
    for (int c = 0; c < 4; c++) {
      uint4 u = *(const uint4*)&vrow[c * 8];
      unsigned uu0 = u.x, uu1 = u.y, uu2 = u.z, uu3 = u.w;
      VT[(c * 8 + 0) * 72 + lane] = (u16)(uu0 & 0xffff);
      VT[(c * 8 + 1) * 72 + lane] = (u16)(uu0 >> 16);
      VT[(c * 8 + 2) * 72 + lane] = (u16)(uu1 & 0xffff);
      VT[(c * 8 + 3) * 72 + lane] = (u16)(uu1 >> 16);
      VT[(c * 8 + 4) * 72 + lane] = (u16)(uu2 & 0xffff);
      VT[(c * 8 + 5) * 72 + lane] = (u16)(uu2 >> 16);
      VT[(c * 8 + 6) * 72 + lane] = (u16)(uu3 & 0xffff);
      VT[(c * 8 + 7) * 72 + lane] = (u16)(uu3 >> 16);
    }
  }

  short8 kf[4], qf[4];
#pragma unroll
  for (int mi = 0; mi < 4; mi++)
    kf[mi] = *(const short8*)(base + 512 + (size_t)(mi * 16 + col) * 1536 + quad * 8);
#pragma unroll
  for (int ni = 0; ni < 4; ni++)
    qf[ni] = *(const short8*)(base + (size_t)(ni * 16 + col) * 1536 + quad * 8);

  floatx4 st[4][4];
#pragma unroll
  for (int mi = 0; mi < 4; mi++)
#pragma unroll
    for (int ni = 0; ni < 4; ni++) st[mi][ni] = (floatx4){0.f, 0.f, 0.f, 0.f};
#pragma unroll
  for (int mi = 0; mi < 4; mi++)
#pragma unroll
    for (int ni = 0; ni < 4; ni++)
      st[mi][ni] = __builtin_amdgcn_mfma_f32_16x16x32_bf16(kf[mi], qf[ni], st[mi][ni], 0, 0, 0);

  const float scale = 0.17677669529663687f;  // 32^-0.5
  float invq[4];
#pragma unroll
  for (int ni = 0; ni < 4; ni++) {
    int q = ni * 16 + col;
    unsigned long long mw = maskbits[widx * 64 + q];
    const float* rp = rpbT + ((size_t)head * 64 + q) * 64;
    float mx = -1e30f;
#pragma unroll
    for (int mi = 0; mi < 4; mi++) {
      floatx4 r4 = *(const floatx4*)&rp[mi * 16 + quad * 4];
#pragma unroll
      for (int r = 0; r < 4; r++) {
        int key = mi * 16 + quad * 4 + r;
        float s = st[mi][ni][r] * scale + r4[r];
        s -= ((mw >> key) & 1ull) ? 100.f : 0.f;
        st[mi][ni][r] = s;
        mx = fmaxf(mx, s);
      }
    }
    mx = fmaxf(mx, __shfl_xor(mx, 16));
    mx = fmaxf(mx, __shfl_xor(mx, 32));
    float sum = 0.f;
#pragma unroll
    for (int mi = 0; mi < 4; mi++) {
      float e0 = __expf(st[mi][ni][0] - mx);
      float e1 = __expf(st[mi][ni][1] - mx);
      float e2 = __expf(st[mi][ni][2] - mx);
      float e3 = __expf(st[mi][ni][3] - mx);
      sum += e0 + e1 + e2 + e3;
      ushort4 pk;
      pk.x = f2bf(e0); pk.y = f2bf(e1); pk.z = f2bf(e2); pk.w = f2bf(e3);
      *(ushort4*)&P[q * 72 + mi * 16 + quad * 4] = pk;
    }
    sum += __shfl_xor(sum, 16);
    sum += __shfl_xor(sum, 32);
    invq[ni] = 1.f / sum;
  }

  floatx4 o[2][4];
#pragma unroll
  for (int mt = 0; mt < 2; mt++)
#pragma unroll
    for (int nt = 0; nt < 4; nt++) o[mt][nt] = (floatx4){0.f, 0.f, 0.f, 0.f};
#pragma unroll
  for (int kc = 0; kc < 2; kc++) {
    short8 vf0 = *(const short8*)&VT[(col) * 72 + kc * 32 + quad * 8];
    short8 vf1 = *(const short8*)&VT[(16 + col) * 72 + kc * 32 + quad * 8];
#pragma unroll
    for (int nt = 0; nt < 4; nt++) {
      short8 pf = *(const short8*)&P[(nt * 16 + col) * 72 + kc * 32 + quad * 8];
      o[0][nt] = __builtin_amdgcn_mfma_f32_16x16x32_bf16(vf0, pf, o[0][nt], 0, 0, 0);
      o[1][nt] = __builtin_amdgcn_mfma_f32_16x16x32_bf16(vf1, pf, o[1][nt], 0, 0, 0);
    }
  }

#pragma unroll
  for (int mt = 0; mt < 2; mt++)
#pragma unroll
    for (int nt = 0; nt < 4; nt++) {
      int q = nt * 16 + col;
      float iv = invq[nt];
      ushort4 pk;
      pk.x = f2bf(o[mt][nt][0] * iv);
      pk.y = f2bf(o[mt][nt][1] * iv);
      pk.z = f2bf(o[mt][nt][2] * iv);
      pk.w = f2bf(o[mt][nt][3] * iv);
      *(ushort4*)&out[((size_t)w_ * 64 + q) * 512 + head * 32 + mt * 16 + quad * 4] = pk;
    }
}

// ---------- launch ----------
extern "C" void kernel_launch(void* const* d_in, const int* in_sizes, int n_in,
                              void* d_out, int out_size, void* d_ws, size_t ws_size,
                              hipStream_t stream) {
  const float* x      = (const float*)d_in[0];
  const float* cond   = (const float*)d_in[1];
  const float* n1w    = (const float*)d_in[2];
  const float* n1b    = (const float*)d_in[3];
  const float* qkv_w  = (const float*)d_in[4];
  const float* qkv_b  = (const float*)d_in[5];
  const float* rpb    = (const float*)d_in[6];
  const float* proj_w = (const float*)d_in[7];
  const float* proj_b = (const float*)d_in[8];
  const float* n2w    = (const float*)d_in[9];
  const float* n2b    = (const float*)d_in[10];
  const float* fc1_w  = (const float*)d_in[11];
  const float* fc1_b  = (const float*)d_in[12];
  const float* fc2_w  = (const float*)d_in[13];
  const float* fc2_b  = (const float*)d_in[14];
  const float* ada_w  = (const float*)d_in[15];
  const float* ada_b  = (const float*)d_in[16];
  float* out = (float*)d_out;
  char* ws = (char*)d_ws;

  // workspace layout (bytes)
  u16*  qkvw_bf  = (u16*)(ws + 0);              // 1,572,864
  u16*  projw_bf = (u16*)(ws + 1572864);        //   524,288
  u16*  fc1w_bf  = (u16*)(ws + 2097152);        // 2,097,152
  u16*  fc2w_bf  = (u16*)(ws + 4194304);        // 2,097,152
  float* ada     = (float*)(ws + 6291456);      //   393,216
  float* rpbT    = (float*)(ws + 6684672);      //   262,144
  unsigned long long* maskb = (unsigned long long*)(ws + 6946816);  // 8,192
  u16*  hw       = (u16*)(ws + 6955008);        // 33,554,432
  u16*  qkvo     = (u16*)(ws + 40509440);       // 100,663,296
  u16*  attno    = (u16*)(ws + 141172736);      // 33,554,432
  u16*  mlp      = (u16*)(ws + 40509440);       // 134,217,728 (reuses qkvo+attno)
  // total 174,727,168 bytes

  convert_bf16<<<768, 256, 0, stream>>>(qkv_w, qkvw_bf, 196608);
  convert_bf16<<<256, 256, 0, stream>>>(proj_w, projw_bf, 65536);
  convert_bf16<<<1024, 256, 0, stream>>>(fc1_w, fc1w_bf, 262144);
  convert_bf16<<<1024, 256, 0, stream>>>(fc2_w, fc2w_bf, 262144);
  prep_attn<<<dim3(64, 16), 64, 0, stream>>>(rpb, rpbT, maskb);

  ada_kernel<<<dim3(12, 32), 256, 0, stream>>>(cond, ada_w, ada_b, ada);
  ln_mod<0><<<32768, 128, 0, stream>>>(x, ada, n1w, n1b, hw);
  gemm_bf16<0><<<dim3(12, 256), 256, 0, stream>>>(hw, qkvw_bf, qkv_b, 512, 1536,
                                                  qkvo, nullptr, nullptr, nullptr);
  attn_mfma<<<2048, 256, 0, stream>>>(qkvo, rpbT, maskb, attno);
  gemm_bf16<2><<<dim3(4, 256), 256, 0, stream>>>(attno, projw_bf, proj_b, 512, 512,
                                                 nullptr, out, x, ada);
  ln_mod<1><<<32768, 128, 0, stream>>>(out, ada, n2w, n2b, hw);
  gemm_bf16<1><<<dim3(16, 256), 256, 0, stream>>>(hw, fc1w_bf, fc1_b, 512, 2048,
                                                  mlp, nullptr, nullptr, nullptr);
  gemm_bf16<3><<<dim3(4, 256), 256, 0, stream>>>(mlp, fc2w_bf, fc2_b, 2048, 512,
                                                 nullptr, out, nullptr, ada);
}

// Round 4
// 566.166 us; speedup vs baseline: 1.3217x; 1.0470x over previous
//
#include <hip/hip_runtime.h>
#include <math.h>

typedef unsigned short u16;
typedef short short8 __attribute__((ext_vector_type(8)));
typedef float floatx4 __attribute__((ext_vector_type(4)));

#define SS 4
#define C_DIM 512
#define L_TOK 1024   // H*W

// ---------- helpers ----------
static __device__ __forceinline__ u16 f2bf(float f) {
  union { float f; unsigned u; } v; v.f = f;
  unsigned u = v.u;
  unsigned r = (u + 0x7fffu + ((u >> 16) & 1u)) >> 16;  // RNE
  return (u16)r;
}

typedef const __attribute__((address_space(1))) void* gvp;
typedef __attribute__((address_space(3))) void* lvp;
#define ASYNC16(g, l) __builtin_amdgcn_global_load_lds((gvp)(g), (lvp)(l), 16, 0, 0)

// ---------- fp32 -> bf16 weight conversion (all 4 weights in one launch) ----------
// float4 segment bounds: qkv 196608 | proj 65536 | fc1 262144 | fc2 262144
__global__ __launch_bounds__(256) void convert_all(const float* __restrict__ s0,
                                                   const float* __restrict__ s1,
                                                   const float* __restrict__ s2,
                                                   const float* __restrict__ s3,
                                                   u16* __restrict__ d0, u16* __restrict__ d1,
                                                   u16* __restrict__ d2, u16* __restrict__ d3) {
  int i = blockIdx.x * 256 + threadIdx.x;   // < 786432
  const float* src; u16* dst; int off;
  if (i < 196608)      { src = s0; dst = d0; off = i; }
  else if (i < 262144) { src = s1; dst = d1; off = i - 196608; }
  else if (i < 524288) { src = s2; dst = d2; off = i - 262144; }
  else                 { src = s3; dst = d3; off = i - 524288; }
  float4 v = ((const float4*)src)[off];
  ushort4 o;
  o.x = f2bf(v.x); o.y = f2bf(v.y); o.z = f2bf(v.z); o.w = f2bf(v.w);
  ((ushort4*)dst)[off] = o;
}

// ---------- ada = silu(cond) @ ada_w.T + ada_b  [32, 3072] ----------
__global__ __launch_bounds__(256) void ada_kernel(const float* __restrict__ cond,
                                                  const float* __restrict__ w,
                                                  const float* __restrict__ bias,
                                                  float* __restrict__ ada) {
  int b = blockIdx.y;
  int j = blockIdx.x * 256 + threadIdx.x;   // < 3072
  __shared__ float sc[C_DIM];
  for (int c = threadIdx.x; c < C_DIM; c += 256) {
    float v = cond[b * C_DIM + c];
    sc[c] = v / (1.0f + expf(-v));
  }
  __syncthreads();
  const float* wr = w + (size_t)j * C_DIM;
  float acc = 0.f;
  for (int k = 0; k < C_DIM; k += 4) {
    float4 wv = *(const float4*)&wr[k];
    acc += sc[k] * wv.x + sc[k + 1] * wv.y + sc[k + 2] * wv.z + sc[k + 3] * wv.w;
  }
  ada[(size_t)b * 3072 + j] = acc + bias[j];
}

// ---------- rpbT[head][q][k] + per-window mask bitwords ----------
__global__ __launch_bounds__(64) void prep_attn(const float* __restrict__ rpb,
                                                float* __restrict__ rpbT,
                                                unsigned long long* __restrict__ maskbits) {
  int q = blockIdx.x;        // 64
  int head = blockIdx.y;     // 16
  int k = threadIdx.x;       // 64
  int i1 = q >> 3, j1 = q & 7, i2 = k >> 3, j2 = k & 7;
  rpbT[((size_t)head * 64 + q) * 64 + k] =
      rpb[((i1 - i2 + 7) * 15 + (j1 - j2 + 7)) * 16 + head];
  if (head == 0) {
    for (int widx = 0; widx < 16; widx++) {
      int wh = widx >> 2, wwi = widx & 3;
      int hq = wh * 8 + i1, wq = wwi * 8 + j1;
      int hk = wh * 8 + i2, wk = wwi * 8 + j2;
      int rq = ((hq < 24) ? 0 : (hq < 28) ? 1 : 2) * 3 + ((wq < 24) ? 0 : (wq < 28) ? 1 : 2);
      int rk = ((hk < 24) ? 0 : (hk < 28) ? 1 : 2) * 3 + ((wk < 24) ? 0 : (wk < 28) ? 1 : 2);
      unsigned long long m = __ballot(rq != rk);
      if (k == 0) maskbits[widx * 64 + q] = m;
    }
  }
}

// ---------- LN + modulate (+ optional roll/window gather), output bf16 ----------
template <int MODE>
__global__ __launch_bounds__(128) void ln_mod(const float* __restrict__ x,
                                              const float* __restrict__ ada,
                                              const float* __restrict__ nw,
                                              const float* __restrict__ nb,
                                              u16* __restrict__ out) {
  int m = blockIdx.x;           // output row (window layout for MODE 0)
  int b = m >> 10;
  size_t srow;
  if (MODE == 0) {
    int n = m & 63, widx = (m >> 6) & 15;
    int wh = widx >> 2, wwi = widx & 3;
    int i = n >> 3, j = n & 7;
    int hs = (wh * 8 + i + SS) & 31;
    int ws_ = (wwi * 8 + j + SS) & 31;
    srow = (size_t)b * L_TOK + hs * 32 + ws_;
  } else {
    srow = (size_t)m;
  }
  const float* src = x + srow * C_DIM;
  int t = threadIdx.x;
  float4 v = *(const float4*)&src[t * 4];
  float s = v.x + v.y + v.z + v.w;
  float ss = v.x * v.x + v.y * v.y + v.z * v.z + v.w * v.w;
#pragma unroll
  for (int off = 32; off > 0; off >>= 1) {
    s += __shfl_down(s, off);
    ss += __shfl_down(ss, off);
  }
  __shared__ float red[4];
  if ((t & 63) == 0) { red[(t >> 6) * 2] = s; red[(t >> 6) * 2 + 1] = ss; }
  __syncthreads();
  float mean = (red[0] + red[2]) * (1.f / C_DIM);
  float var = (red[1] + red[3]) * (1.f / C_DIM) - mean * mean;
  float rstd = rsqrtf(var + 1e-5f);
  const float* sh = ada + (size_t)b * 3072 + (MODE ? 1536 : 0);
  const float* scm = ada + (size_t)b * 3072 + (MODE ? 2048 : 512);
  int c = t * 4;
  ushort4 o;
  {
    float y;
    y = ((v.x - mean) * rstd * nw[c + 0] + nb[c + 0]) * (1.f + scm[c + 0]) + sh[c + 0]; o.x = f2bf(y);
    y = ((v.y - mean) * rstd * nw[c + 1] + nb[c + 1]) * (1.f + scm[c + 1]) + sh[c + 1]; o.y = f2bf(y);
    y = ((v.z - mean) * rstd * nw[c + 2] + nb[c + 2]) * (1.f + scm[c + 2]) + sh[c + 2]; o.z = f2bf(y);
    y = ((v.w - mean) * rstd * nw[c + 3] + nb[c + 3]) * (1.f + scm[c + 3]) + sh[c + 3]; o.w = f2bf(y);
  }
  *(ushort4*)&out[(size_t)m * C_DIM + c] = o;
}

// ---------- bf16 MFMA GEMM: out[M,N] = A[M,K] @ Bw[N,K]^T + bias ----------
// XCD-aware swizzle: each XCD owns a contiguous row-tile range (x fastest),
// so A-tile sharers + the full weight tile stay in one XCD's L2.
// C^T register layout (mfma(a=W, b=X)) -> packed epilogue stores.
// EPI 0: bias -> bf16             (qkv)
// EPI 1: bias, tanh-GELU -> bf16  (fc1)
// EPI 2: bias, window-reverse + roll scatter, x + g_msa*v -> fp32 d_out (proj)
// EPI 3: bias, d_out += g_mlp*v in place (fc2)
template <int EPI>
__global__ __launch_bounds__(256, 2) void gemm_bf16(
    const u16* __restrict__ A, const u16* __restrict__ Bw,
    const float* __restrict__ bias, int K, int N,
    u16* __restrict__ outBf, float* __restrict__ outF,
    const float* __restrict__ resid, const float* __restrict__ ada) {
  __shared__ __align__(16) u16 lA[2][128 * 32];
  __shared__ __align__(16) u16 lB[2][128 * 32];
  const int tid = threadIdx.x;
  const int lane = tid & 63, wave = tid >> 6;
  const int wr = wave >> 1, wc = wave & 1;
  // XCD swizzle (bijection; correctness does not depend on dispatch mapping)
  const int gx = gridDim.x;
  const int id = blockIdx.y * gx + blockIdx.x;
  const int per = (gx * gridDim.y) >> 3;
  const int nid = (id & 7) * per + (id >> 3);
  const int rowA0 = (nid / gx) * 128;
  const int colB0 = (nid % gx) * 128;
  floatx4 acc[4][4];
#pragma unroll
  for (int a = 0; a < 4; a++)
#pragma unroll
    for (int b = 0; b < 4; b++) acc[a][b] = (floatx4){0.f, 0.f, 0.f, 0.f};

  const int r0 = tid >> 2, c0 = (tid & 3) * 8;  // staging chunk (16B = 8 bf16)
  const int q = lane >> 4, fr = lane & 15;

  const u16* gA = &A[(size_t)(rowA0 + r0) * K + c0];
  const u16* gB = &Bw[(size_t)(colB0 + r0) * K + c0];
  const size_t up = (size_t)64 * K;  // row-half stride in global
  u16* lA0 = &lA[0][wave * 512];
  u16* lB0 = &lB[0][wave * 512];

  for (int k0 = 0; k0 < K; k0 += 64) {
    ASYNC16(gA + k0, lA0);
    ASYNC16(gA + k0 + up, lA0 + 2048);
    ASYNC16(gA + k0 + 32, lA0 + 4096);
    ASYNC16(gA + k0 + 32 + up, lA0 + 6144);
    ASYNC16(gB + k0, lB0);
    ASYNC16(gB + k0 + up, lB0 + 2048);
    ASYNC16(gB + k0 + 32, lB0 + 4096);
    ASYNC16(gB + k0 + 32 + up, lB0 + 6144);
    __syncthreads();
#pragma unroll
    for (int kc = 0; kc < 2; kc++) {
      short8 xf[4], wf[4];
#pragma unroll
      for (int mi = 0; mi < 4; mi++)
        xf[mi] = *(const short8*)&lA[kc][(wr * 64 + mi * 16 + fr) * 32 + q * 8];
#pragma unroll
      for (int ni = 0; ni < 4; ni++)
        wf[ni] = *(const short8*)&lB[kc][(wc * 64 + ni * 16 + fr) * 32 + q * 8];
#pragma unroll
      for (int mi = 0; mi < 4; mi++)
#pragma unroll
        for (int ni = 0; ni < 4; ni++)
          acc[mi][ni] = __builtin_amdgcn_mfma_f32_16x16x32_bf16(wf[ni], xf[mi], acc[mi][ni], 0, 0, 0);
    }
    __syncthreads();
  }

  // acc[mi][ni][r]: C[row = rowA0+wr*64+mi*16+fr][col = colB0+wc*64+ni*16+q*4+r]
#pragma unroll
  for (int mi = 0; mi < 4; mi++) {
    int row = rowA0 + wr * 64 + mi * 16 + fr;
#pragma unroll
    for (int ni = 0; ni < 4; ni++) {
      int col0 = colB0 + wc * 64 + ni * 16 + q * 4;
      float4 bv = *(const float4*)&bias[col0];
      float v0 = acc[mi][ni][0] + bv.x;
      float v1 = acc[mi][ni][1] + bv.y;
      float v2 = acc[mi][ni][2] + bv.z;
      float v3 = acc[mi][ni][3] + bv.w;
      if (EPI == 1) {  // tanh-form GELU
        v0 = __fdividef(v0, 1.f + __expf(-v0 * (1.59576912f + 0.07135481f * v0 * v0)));
        v1 = __fdividef(v1, 1.f + __expf(-v1 * (1.59576912f + 0.07135481f * v1 * v1)));
        v2 = __fdividef(v2, 1.f + __expf(-v2 * (1.59576912f + 0.07135481f * v2 * v2)));
        v3 = __fdividef(v3, 1.f + __expf(-v3 * (1.59576912f + 0.07135481f * v3 * v3)));
      }
      if (EPI == 0 || EPI == 1) {
        ushort4 pk;
        pk.x = f2bf(v0); pk.y = f2bf(v1); pk.z = f2bf(v2); pk.w = f2bf(v3);
        *(ushort4*)&outBf[(size_t)row * N + col0] = pk;
      } else if (EPI == 2) {
        int b = row >> 10;
        int n = row & 63, widx = (row >> 6) & 15;
        int wh = widx >> 2, wwi = widx & 3;
        int i = n >> 3, j = n & 7;
        int hd = (wh * 8 + i + SS) & 31;
        int wd = (wwi * 8 + j + SS) & 31;
        size_t dst = ((size_t)b * L_TOK + hd * 32 + wd) * C_DIM + col0;
        float4 rs = *(const float4*)&resid[dst];
        float4 g = *(const float4*)&ada[(size_t)b * 3072 + 1024 + col0];
        float4 o;
        o.x = rs.x + g.x * v0; o.y = rs.y + g.y * v1;
        o.z = rs.z + g.z * v2; o.w = rs.w + g.w * v3;
        *(float4*)&outF[dst] = o;
      } else {
        int b = row >> 10;
        size_t dst = (size_t)row * C_DIM + col0;
        float4 cur = *(const float4*)&outF[dst];
        float4 g = *(const float4*)&ada[(size_t)b * 3072 + 2560 + col0];
        float4 o;
        o.x = cur.x + g.x * v0; o.y = cur.y + g.y * v1;
        o.z = cur.z + g.z * v2; o.w = cur.w + g.w * v3;
        *(float4*)&outF[dst] = o;
      }
    }
  }
}

// ---------- MFMA windowed attention: one single-wave block per (window, head) ----------
// 13.8 KB LDS/block -> ~11 blocks/CU; no false inter-wave barriers.
__global__ __launch_bounds__(64, 4) void attn_mfma(const u16* __restrict__ qkv,
                                                   const float* __restrict__ rpbT,
                                                   const unsigned long long* __restrict__ maskbits,
                                                   u16* __restrict__ out) {
  __shared__ __align__(16) u16 VT[32 * 72];  // V^T, stride 72
  __shared__ __align__(16) u16 P[64 * 72];   // P, stride 72
  const int lane = threadIdx.x;
  const int col = lane & 15, quad = lane >> 4;
  const int id = blockIdx.x;                 // 8192 = 512 windows * 16 heads
  const int w_ = id >> 4, head = id & 15;
  const int widx = w_ & 15;
  const u16* base = qkv + (size_t)w_ * 64 * 1536 + head * 32;

  {
    const u16* vrow = base + 1024 + (size_t)lane * 1536;
#pragma unroll
    for (int c = 0; c < 4; c++) {
      uint4 u = *(const uint4*)&vrow[c * 8];
      unsigned uu0 = u.x, uu1 = u.y, uu2 = u.z, uu3 = u.w;
      VT[(c * 8 + 0) * 72 + lane] = (u16)(uu0 & 0xffff);
      VT[(c * 8 + 1) * 72 + lane] = (u16)(uu0 >> 16);
      VT[(c * 8 + 2) * 72 + lane] = (u16)(uu1 & 0xffff);
      VT[(c * 8 + 3) * 72 + lane] = (u16)(uu1 >> 16);
      VT[(c * 8 + 4) * 72 + lane] = (u16)(uu2 & 0xffff);
      VT[(c * 8 + 5) * 72 + lane] = (u16)(uu2 >> 16);
      VT[(c * 8 + 6) * 72 + lane] = (u16)(uu3 & 0xffff);
      VT[(c * 8 + 7) * 72 + lane] = (u16)(uu3 >> 16);
    }
  }

  short8 kf[4], qf[4];
#pragma unroll
  for (int mi = 0; mi < 4; mi++)
    kf[mi] = *(const short8*)(base + 512 + (size_t)(mi * 16 + col) * 1536 + quad * 8);
#pragma unroll
  for (int ni = 0; ni < 4; ni++)
    qf[ni] = *(const short8*)(base + (size_t)(ni * 16 + col) * 1536 + quad * 8);

  floatx4 st[4][4];
#pragma unroll
  for (int mi = 0; mi < 4; mi++)
#pragma unroll
    for (int ni = 0; ni < 4; ni++) st[mi][ni] = (floatx4){0.f, 0.f, 0.f, 0.f};
#pragma unroll
  for (int mi = 0; mi < 4; mi++)
#pragma unroll
    for (int ni = 0; ni < 4; ni++)
      st[mi][ni] = __builtin_amdgcn_mfma_f32_16x16x32_bf16(kf[mi], qf[ni], st[mi][ni], 0, 0, 0);

  const float scale = 0.17677669529663687f;  // 32^-0.5
  float invq[4];
#pragma unroll
  for (int ni = 0; ni < 4; ni++) {
    int q = ni * 16 + col;
    unsigned long long mw = maskbits[widx * 64 + q];
    const float* rp = rpbT + ((size_t)head * 64 + q) * 64;
    float mx = -1e30f;
#pragma unroll
    for (int mi = 0; mi < 4; mi++) {
      floatx4 r4 = *(const floatx4*)&rp[mi * 16 + quad * 4];
#pragma unroll
      for (int r = 0; r < 4; r++) {
        int key = mi * 16 + quad * 4 + r;
        float s = st[mi][ni][r] * scale + r4[r];
        s -= ((mw >> key) & 1ull) ? 100.f : 0.f;
        st[mi][ni][r] = s;
        mx = fmaxf(mx, s);
      }
    }
    mx = fmaxf(mx, __shfl_xor(mx, 16));
    mx = fmaxf(mx, __shfl_xor(mx, 32));
    float sum = 0.f;
#pragma unroll
    for (int mi = 0; mi < 4; mi++) {
      float e0 = __expf(st[mi][ni][0] - mx);
      float e1 = __expf(st[mi][ni][1] - mx);
      float e2 = __expf(st[mi][ni][2] - mx);
      float e3 = __expf(st[mi][ni][3] - mx);
      sum += e0 + e1 + e2 + e3;
      ushort4 pk;
      pk.x = f2bf(e0); pk.y = f2bf(e1); pk.z = f2bf(e2); pk.w = f2bf(e3);
      *(ushort4*)&P[q * 72 + mi * 16 + quad * 4] = pk;
    }
    sum += __shfl_xor(sum, 16);
    sum += __shfl_xor(sum, 32);
    invq[ni] = 1.f / sum;
  }
  __syncthreads();

  floatx4 o[2][4];
#pragma unroll
  for (int mt = 0; mt < 2; mt++)
#pragma unroll
    for (int nt = 0; nt < 4; nt++) o[mt][nt] = (floatx4){0.f, 0.f, 0.f, 0.f};
#pragma unroll
  for (int kc = 0; kc < 2; kc++) {
    short8 vf0 = *(const short8*)&VT[(col) * 72 + kc * 32 + quad * 8];
    short8 vf1 = *(const short8*)&VT[(16 + col) * 72 + kc * 32 + quad * 8];
#pragma unroll
    for (int nt = 0; nt < 4; nt++) {
      short8 pf = *(const short8*)&P[(nt * 16 + col) * 72 + kc * 32 + quad * 8];
      o[0][nt] = __builtin_amdgcn_mfma_f32_16x16x32_bf16(vf0, pf, o[0][nt], 0, 0, 0);
      o[1][nt] = __builtin_amdgcn_mfma_f32_16x16x32_bf16(vf1, pf, o[1][nt], 0, 0, 0);
    }
  }

#pragma unroll
  for (int mt = 0; mt < 2; mt++)
#pragma unroll
    for (int nt = 0; nt < 4; nt++) {
      int q = nt * 16 + col;
      float iv = invq[nt];
      ushort4 pk;
      pk.x = f2bf(o[mt][nt][0] * iv);
      pk.y = f2bf(o[mt][nt][1] * iv);
      pk.z = f2bf(o[mt][nt][2] * iv);
      pk.w = f2bf(o[mt][nt][3] * iv);
      *(ushort4*)&out[((size_t)w_ * 64 + q) * 512 + head * 32 + mt * 16 + quad * 4] = pk;
    }
}

// ---------- launch ----------
extern "C" void kernel_launch(void* const* d_in, const int* in_sizes, int n_in,
                              void* d_out, int out_size, void* d_ws, size_t ws_size,
                              hipStream_t stream) {
  const float* x      = (const float*)d_in[0];
  const float* cond   = (const float*)d_in[1];
  const float* n1w    = (const float*)d_in[2];
  const float* n1b    = (const float*)d_in[3];
  const float* qkv_w  = (const float*)d_in[4];
  const float* qkv_b  = (const float*)d_in[5];
  const float* rpb    = (const float*)d_in[6];
  const float* proj_w = (const float*)d_in[7];
  const float* proj_b = (const float*)d_in[8];
  const float* n2w    = (const float*)d_in[9];
  const float* n2b    = (const float*)d_in[10];
  const float* fc1_w  = (const float*)d_in[11];
  const float* fc1_b  = (const float*)d_in[12];
  const float* fc2_w  = (const float*)d_in[13];
  const float* fc2_b  = (const float*)d_in[14];
  const float* ada_w  = (const float*)d_in[15];
  const float* ada_b  = (const float*)d_in[16];
  float* out = (float*)d_out;
  char* ws = (char*)d_ws;

  // workspace layout (bytes)
  u16*  qkvw_bf  = (u16*)(ws + 0);              // 1,572,864
  u16*  projw_bf = (u16*)(ws + 1572864);        //   524,288
  u16*  fc1w_bf  = (u16*)(ws + 2097152);        // 2,097,152
  u16*  fc2w_bf  = (u16*)(ws + 4194304);        // 2,097,152
  float* ada     = (float*)(ws + 6291456);      //   393,216
  float* rpbT    = (float*)(ws + 6684672);      //   262,144
  unsigned long long* maskb = (unsigned long long*)(ws + 6946816);  // 8,192
  u16*  hw       = (u16*)(ws + 6955008);        // 33,554,432
  u16*  qkvo     = (u16*)(ws + 40509440);       // 100,663,296
  u16*  attno    = (u16*)(ws + 141172736);      // 33,554,432
  u16*  mlp      = (u16*)(ws + 40509440);       // 134,217,728 (reuses qkvo+attno)
  // total 174,727,168 bytes

  convert_all<<<3072, 256, 0, stream>>>(qkv_w, proj_w, fc1_w, fc2_w,
                                        qkvw_bf, projw_bf, fc1w_bf, fc2w_bf);
  prep_attn<<<dim3(64, 16), 64, 0, stream>>>(rpb, rpbT, maskb);

  ada_kernel<<<dim3(12, 32), 256, 0, stream>>>(cond, ada_w, ada_b, ada);
  ln_mod<0><<<32768, 128, 0, stream>>>(x, ada, n1w, n1b, hw);
  gemm_bf16<0><<<dim3(12, 256), 256, 0, stream>>>(hw, qkvw_bf, qkv_b, 512, 1536,
                                                  qkvo, nullptr, nullptr, nullptr);
  attn_mfma<<<8192, 64, 0, stream>>>(qkvo, rpbT, maskb, attno);
  gemm_bf16<2><<<dim3(4, 256), 256, 0, stream>>>(attno, projw_bf, proj_b, 512, 512,
                                                 nullptr, out, x, ada);
  ln_mod<1><<<32768, 128, 0, stream>>>(out, ada, n2w, n2b, hw);
  gemm_bf16<1><<<dim3(16, 256), 256, 0, stream>>>(hw, fc1w_bf, fc1_b, 512, 2048,
                                                  mlp, nullptr, nullptr, nullptr);
  gemm_bf16<3><<<dim3(4, 256), 256, 0, stream>>>(mlp, fc2w_bf, fc2_b, 2048, 512,
                                                 nullptr, out, nullptr, ada);
}